// Round 15
// baseline (158.429 us; speedup 1.0000x reference)
//
#include <hip/hip_runtime.h>
#include <math.h>

#define PI_F 3.14159265358979323846f
#define TWO_PI_F 6.28318530717958647692f

// problem sizes
constexpr int Bn = 32, Cn = 64, On = 64, Hn = 128, Wn = 128;

// workspace float offsets (small region < WSO_BIG)
constexpr size_t WSO_FLAT  = 0;                        // 32*2048 = 65536
constexpr size_t WSO_CORR  = 65536;                    // 32*64   = 2048
constexpr size_t WSO_BIG   = 81920;
constexpr size_t SZ_QTR    = (size_t)2097152;          // 2M floats
constexpr size_t WSO_XF    = WSO_BIG + SZ_QTR;         // [2048][32][16][2]
constexpr size_t WSO_OUTFT = WSO_BIG + 4 * SZ_QTR;     // [2048][1024] B-frag order

// ================= compile-time tables =================
struct Tabs {
  float ktw[128][40];
  float cfth[128][8];
};

constexpr double D_PI = 3.14159265358979323846;

constexpr double d_red(double x) {
  while (x >  D_PI) x -= 2.0 * D_PI;
  while (x < -D_PI) x += 2.0 * D_PI;
  return x;
}
constexpr double d_sin(double x) {
  x = d_red(x);
  double x2 = x * x, t = x, s = x;
  for (int n = 1; n <= 10; n++) { t *= -x2 / (double)((2 * n) * (2 * n + 1)); s += t; }
  return s;
}
constexpr double d_cos(double x) {
  x = d_red(x);
  double x2 = x * x, t = 1.0, s = 1.0;
  for (int n = 1; n <= 10; n++) { t *= -x2 / (double)((2 * n - 1) * (2 * n)); s += t; }
  return s;
}

constexpr Tabs make_tabs() {
  Tabs T{};
  double twc[128] = {}, tws[128] = {};
  for (int r = 0; r < 128; r++) {
    double a = 2.0 * D_PI * (double)r / 128.0;
    twc[r] = d_cos(a); tws[r] = d_sin(a);
  }
  for (int kx = 0; kx < 16; kx++)
    for (int w = 0; w < 128; w++) {
      int r = (kx * w) & 127;
      T.ktw[w][2 * kx]     = (float)twc[r];
      T.ktw[w][2 * kx + 1] = (float)(-tws[r]);
    }
  double node[8] = {}, theta[8] = {};
  for (int m = 0; m < 8; m++) { theta[m] = (2.0 * m + 1.0) * D_PI / 16.0; node[m] = -d_cos(theta[m]); }
  double Tch[8][8] = {};
  for (int k = 0; k < 8; k++)
    for (int m = 0; m < 8; m++) Tch[k][m] = d_cos((double)k * (D_PI - theta[m]));
  int LE[4][8] = {}, RI[4][8] = {};
  float WL[4][8] = {}, WR[4][8] = {};
  for (int l = 0; l < 4; l++)
    for (int m = 0; m < 8; m++) {
      float tseg = (float)(0.25 * (double)l + 0.125 * (node[m] + 1.0));
      int ri = (int)(tseg * 127.0f) - 2; if (ri < 0) ri = 0;
      while (ri < 127 && ((float)ri * (1.0f / 127.0f)) < tseg) ri++;
      int le = ri - 1; if (le < 0) le = 0;
      float tl = (float)le * (1.0f / 127.0f), tr = (float)ri * (1.0f / 127.0f);
      float den = (tr - tl < 1e-8f) ? 1.0f : (tr - tl);
      float wr = (tseg - tl) / den;
      LE[l][m] = le; RI[l][m] = ri; WR[l][m] = wr; WL[l][m] = 1.0f - wr;
    }
  for (int p = 0; p < 2; p++)
    for (int f = 0; f < 4; f++) {
      double fval = (p == 0) ? (double)f
                             : ((f == 0) ? 0.0 : (f == 1) ? 1.0 : (f == 2) ? -2.0 : -1.0);
      double wp = fval * (2.0 * D_PI * 0.125);
      double Wr[8] = {}, Wi[8] = {};
      for (int k = 0; k < 8; k++) {
        double sr = 0.0, si = 0.0;
        for (int m = 0; m < 8; m++) {
          sr += Tch[k][m] * d_cos(node[m] * wp);
          si += Tch[k][m] * (-d_sin(node[m] * wp));
        }
        Wr[k] = sr * 0.125; Wi[k] = si * 0.125;
      }
      for (int l = 0; l < 4; l++) {
        double ph = -2.0 * D_PI * (0.25 * (double)l) * fval;
        double cr = d_cos(ph), ci = d_sin(ph);
        for (int m = 0; m < 8; m++) {
          double coefR = Wr[m] * cr - Wi[m] * ci;
          double coefI = Wr[m] * ci + Wi[m] * cr;
          int le = LE[l][m], ri = RI[l][m];
          if (p == 0) {
            T.ktw[le][32 + f] += (float)(WL[l][m] * coefR);
            T.ktw[le][36 + f] += (float)(WL[l][m] * coefI);
            T.ktw[ri][32 + f] += (float)(WR[l][m] * coefR);
            T.ktw[ri][36 + f] += (float)(WR[l][m] * coefI);
          } else {
            T.cfth[le][f]     += (float)(WL[l][m] * coefR);
            T.cfth[le][4 + f] += (float)(WL[l][m] * coefI);
            T.cfth[ri][f]     += (float)(WR[l][m] * coefR);
            T.cfth[ri][4 + f] += (float)(WR[l][m] * coefI);
          }
        }
      }
    }
  return T;
}

// ---- bf16 split helpers: compile-time (bit-trick RNE) ----
constexpr unsigned short cf2bf(float f) {
  unsigned u = __builtin_bit_cast(unsigned, f);
  u += 0x7FFFu + ((u >> 16) & 1u);
  return (unsigned short)(u >> 16);
}
constexpr float cbf2f(unsigned short h) {
  return __builtin_bit_cast(float, (unsigned)h << 16);
}

// -------- cfth coefficient table (f32) --------
struct CfthT { float v[128][8]; };
constexpr CfthT make_cfth() {
  CfthT C{};
  Tabs T = make_tabs();
  for (int h = 0; h < 128; h++)
    for (int q = 0; q < 8; q++) C.v[h][q] = T.cfth[h][q];
  return C;
}
__constant__ CfthT g_cfth = make_cfth();

// -------- stage A B-table --------
struct alignas(16) BTab {
  unsigned short v[4][2][3][64][8];   // [kstep][hi/lo][jtile][lane][j]
};
constexpr BTab make_btab() {
  BTab B{};
  Tabs T = make_tabs();
  for (int ks = 0; ks < 4; ks++)
    for (int jt = 0; jt < 3; jt++)
      for (int lane = 0; lane < 64; lane++)
        for (int j = 0; j < 8; j++) {
          int col = jt * 16 + (lane & 15);
          int k = ks * 32 + (lane >> 4) * 8 + j;
          float val = (col < 40) ? T.ktw[k][col] : 0.0f;
          unsigned short h = cf2bf(val);
          B.v[ks][0][jt][lane][j] = h;
          B.v[ks][1][jt][lane][j] = cf2bf(val - cbf2f(h));
        }
  return B;
}
__constant__ BTab g_btab = make_btab();

// -------- fwd B-part A-table: TB[64 m=(ri*32+j)][256 k=(2h+u)] --------
struct alignas(16) TBTab {
  unsigned short v[4][8][2][64][8];   // [mtile][kstep][hi/lo][lane][j]
};
constexpr TBTab make_tbtab() {
  TBTab T{};
  double twc[128] = {}, tws[128] = {};
  for (int r = 0; r < 128; r++) {
    double a = 2.0 * D_PI * (double)r / 128.0;
    twc[r] = d_cos(a); tws[r] = d_sin(a);
  }
  for (int mt = 0; mt < 4; mt++)
    for (int ks = 0; ks < 8; ks++)
      for (int lane = 0; lane < 64; lane++)
        for (int js = 0; js < 8; js++) {
          int m = mt * 16 + (lane & 15);
          int j = m & 31, ri = m >> 5;
          int k = ks * 32 + (lane >> 4) * 8 + js;
          int h = k >> 1, u = k & 1;
          int ky = (j < 16) ? j : j + 96;
          int idx = (ky * h) & 127;
          double c = twc[idx], s = tws[idx];
          double val = (ri == 0) ? ((u == 0) ? c : s)
                                 : ((u == 0) ? -s : c);
          float f = (float)val;
          unsigned short hi = cf2bf(f);
          T.v[mt][ks][0][lane][js] = hi;
          T.v[mt][ks][1][lane][js] = cf2bf(f - cbf2f(hi));
        }
  return T;
}
__constant__ TBTab g_tbtab = make_tbtab();

// -------- stage DE GEMM1 A-table --------
struct alignas(16) W1Tab {
  unsigned short v[16][2][2][64][8];  // [mtile][kstep][hi/lo][lane][j]
};
constexpr W1Tab make_w1tab() {
  W1Tab T{};
  double twc[128] = {}, tws[128] = {};
  for (int r = 0; r < 128; r++) {
    double a = 2.0 * D_PI * (double)r / 128.0;
    twc[r] = d_cos(a); tws[r] = d_sin(a);
  }
  for (int mt = 0; mt < 16; mt++)
    for (int ks = 0; ks < 2; ks++)
      for (int lane = 0; lane < 64; lane++)
        for (int j = 0; j < 8; j++) {
          int r = mt * 16 + (lane & 15);
          int k = ks * 32 + (lane >> 4) * 8 + j;
          int jj = k >> 1, u = k & 1;
          int ky = (jj < 16) ? jj : jj + 96;
          int h = r & 127;
          int idx = (ky * h) & 127;
          double c = twc[idx], s = tws[idx];
          double val = (r < 128) ? ((u == 0) ? c : -s)
                                 : ((u == 0) ? s : c);
          float f = (float)(val * (1.0 / 128.0));
          unsigned short hi = cf2bf(f);
          T.v[mt][ks][0][lane][j] = hi;
          T.v[mt][ks][1][lane][j] = cf2bf(f - cbf2f(hi));
        }
  return T;
}
__constant__ W1Tab g_w1tab = make_w1tab();

// -------- stage DE GEMM2 B-table --------
struct alignas(16) W2Tab {
  unsigned short v[8][2][64][8];      // [ntile][hi/lo][lane][j]
};
constexpr W2Tab make_w2tab() {
  W2Tab T{};
  double twc[128] = {}, tws[128] = {};
  for (int r = 0; r < 128; r++) {
    double a = 2.0 * D_PI * (double)r / 128.0;
    twc[r] = d_cos(a); tws[r] = d_sin(a);
  }
  for (int nt = 0; nt < 8; nt++)
    for (int lane = 0; lane < 64; lane++)
      for (int j = 0; j < 8; j++) {
        int w = nt * 16 + (lane & 15);
        int k = (lane >> 4) * 8 + j;
        int kx = k >> 1, u = k & 1;
        double val;
        if (kx == 0) val = (u == 0) ? 1.0 : 0.0;
        else {
          int idx = (kx * w) & 127;
          val = (u == 0) ? 2.0 * twc[idx] : -2.0 * tws[idx];
        }
        float f = (float)(val * (1.0 / 128.0));
        unsigned short hi = cf2bf(f);
        T.v[nt][0][lane][j] = hi;
        T.v[nt][1][lane][j] = cf2bf(f - cbf2f(hi));
      }
  return T;
}
__constant__ W2Tab g_w2tab = make_w2tab();

typedef __attribute__((ext_vector_type(8))) __bf16 bf16x8;
typedef __attribute__((ext_vector_type(8))) unsigned short ushort8;
typedef __attribute__((ext_vector_type(4))) float f32x4;

// ---- runtime bf16 helpers: native casts (v_cvt RNE) ----
__device__ __forceinline__ unsigned short f2bf(float f) {
  return __builtin_bit_cast(unsigned short, (__bf16)f);
}
__device__ __forceinline__ float bf2f(unsigned short h) {
  return (float)__builtin_bit_cast(__bf16, h);
}

// ---------------- fwd: fused stage A + stage B + CFT H-pass (round-12 best form) ----------------
__global__ __launch_bounds__(256) void k_fwd(const float* __restrict__ x,
                                             float* __restrict__ xf,
                                             float* __restrict__ flat) {
  __shared__ unsigned xwlp[128][34];   // [h][j=2kx+u] packed (hi | lo<<16)
  __shared__ float cftl[128][9];
  __shared__ float cpart[8][33];
  int t = threadIdx.x;
  int lane = t & 63, wid = t >> 6;
  int bc = blockIdx.x;
  const float* xb = x + (size_t)bc * 16384;
  int r = lane & 15, kg = lane >> 4;
  const float* a0 = xb + (wid * 32 + r) * 128 + kg * 8;
  const float* a1 = a0 + 16 * 128;

  float4 xa[16];
  #pragma unroll
  for (int ks = 0; ks < 4; ks++) {
    xa[2 * ks]     = *reinterpret_cast<const float4*>(a0 + ks * 32);
    xa[2 * ks + 1] = *reinterpret_cast<const float4*>(a0 + ks * 32 + 4);
  }
  #pragma unroll
  for (int ks = 0; ks < 4; ks++) {
    xa[8 + 2 * ks]     = *reinterpret_cast<const float4*>(a1 + ks * 32);
    xa[8 + 2 * ks + 1] = *reinterpret_cast<const float4*>(a1 + ks * 32 + 4);
  }

  bf16x8 ahi[2][4], alo[2][4];
  #pragma unroll
  for (int tl = 0; tl < 2; tl++) {
    #pragma unroll
    for (int ks = 0; ks < 4; ks++) {
      const float* p0 = reinterpret_cast<const float*>(&xa[tl * 8 + 2 * ks]);
      const float* p1 = reinterpret_cast<const float*>(&xa[tl * 8 + 2 * ks + 1]);
      ushort8 hu, lu;
      #pragma unroll
      for (int j = 0; j < 8; j++) {
        float v = (j < 4) ? p0[j] : p1[j - 4];
        unsigned short h = f2bf(v);
        hu[j] = h;
        lu[j] = f2bf(v - bf2f(h));
      }
      ahi[tl][ks] = __builtin_bit_cast(bf16x8, hu);
      alo[tl][ks] = __builtin_bit_cast(bf16x8, lu);
    }
  }

  f32x4 acc[2][3];
  #pragma unroll
  for (int tl = 0; tl < 2; tl++)
    #pragma unroll
    for (int jt = 0; jt < 3; jt++) acc[tl][jt] = f32x4{0.f, 0.f, 0.f, 0.f};
  #pragma unroll
  for (int jt = 0; jt < 3; jt++) {
    #pragma unroll
    for (int ks = 0; ks < 4; ks++) {
      bf16x8 bhi = __builtin_bit_cast(bf16x8,
          *reinterpret_cast<const ushort8*>(&g_btab.v[ks][0][jt][lane][0]));
      bf16x8 blo = __builtin_bit_cast(bf16x8,
          *reinterpret_cast<const ushort8*>(&g_btab.v[ks][1][jt][lane][0]));
      acc[0][jt] = __builtin_amdgcn_mfma_f32_16x16x32_bf16(ahi[0][ks], bhi, acc[0][jt], 0, 0, 0);
      acc[1][jt] = __builtin_amdgcn_mfma_f32_16x16x32_bf16(ahi[1][ks], bhi, acc[1][jt], 0, 0, 0);
      acc[0][jt] = __builtin_amdgcn_mfma_f32_16x16x32_bf16(alo[0][ks], bhi, acc[0][jt], 0, 0, 0);
      acc[1][jt] = __builtin_amdgcn_mfma_f32_16x16x32_bf16(alo[1][ks], bhi, acc[1][jt], 0, 0, 0);
      acc[0][jt] = __builtin_amdgcn_mfma_f32_16x16x32_bf16(ahi[0][ks], blo, acc[0][jt], 0, 0, 0);
      acc[1][jt] = __builtin_amdgcn_mfma_f32_16x16x32_bf16(ahi[1][ks], blo, acc[1][jt], 0, 0, 0);
    }
  }
  {
    int col = lane & 15, rq = lane >> 4;
    #pragma unroll
    for (int tl = 0; tl < 2; tl++) {
      int rt = wid * 2 + tl;
      #pragma unroll
      for (int jt = 0; jt < 3; jt++) {
        #pragma unroll
        for (int i = 0; i < 4; i++) {
          int rl = rt * 16 + rq * 4 + i;
          float v = acc[tl][jt][i];
          if (jt < 2) {
            unsigned short hi = f2bf(v);
            unsigned short lo = f2bf(v - bf2f(hi));
            xwlp[rl][jt * 16 + col] = ((unsigned)lo << 16) | (unsigned)hi;
          } else if (col < 8) {
            cftl[rl][col] = v;
          }
        }
      }
    }
  }
  __syncthreads();

  {
    int o = t & 31, seg = t >> 5;
    int f1 = o >> 3, f2 = (o >> 1) & 3, ri = o & 1;
    float acc2 = 0.f;
    #pragma unroll
    for (int hh = 0; hh < 16; hh++) {
      int h = seg * 16 + hh;
      float rr = cftl[h][f2], im = cftl[h][4 + f2];
      float kr = g_cfth.v[h][f1], ki = g_cfth.v[h][4 + f1];
      float e0 = ri ? ki : kr;
      float e1 = ri ? kr : -ki;
      acc2 = fmaf(rr, e0, fmaf(im, e1, acc2));
    }
    cpart[seg][o] = acc2;
  }

  {
    int kx = lane & 15, g = lane >> 4;
    f32x4 accA = {0.f, 0.f, 0.f, 0.f};
    f32x4 accB = {0.f, 0.f, 0.f, 0.f};
    #pragma unroll
    for (int ks2 = 0; ks2 < 4; ks2++) {
      #pragma unroll
      for (int half = 0; half < 2; half++) {
        int ks = half * 4 + ks2;
        int h0 = ks * 16 + g * 4;
        ushort8 bhU, blU;
        #pragma unroll
        for (int rr = 0; rr < 4; rr++) {
          uint2 p = *reinterpret_cast<const uint2*>(&xwlp[h0 + rr][2 * kx]);
          bhU[2 * rr]     = (unsigned short)(p.x & 0xFFFFu);
          blU[2 * rr]     = (unsigned short)(p.x >> 16);
          bhU[2 * rr + 1] = (unsigned short)(p.y & 0xFFFFu);
          blU[2 * rr + 1] = (unsigned short)(p.y >> 16);
        }
        bf16x8 bhi = __builtin_bit_cast(bf16x8, bhU);
        bf16x8 blo = __builtin_bit_cast(bf16x8, blU);
        bf16x8 thi = __builtin_bit_cast(bf16x8,
            *reinterpret_cast<const ushort8*>(&g_tbtab.v[wid][ks][0][lane][0]));
        bf16x8 tlo = __builtin_bit_cast(bf16x8,
            *reinterpret_cast<const ushort8*>(&g_tbtab.v[wid][ks][1][lane][0]));
        f32x4& acc3 = half ? accB : accA;
        acc3 = __builtin_amdgcn_mfma_f32_16x16x32_bf16(thi, bhi, acc3, 0, 0, 0);
        acc3 = __builtin_amdgcn_mfma_f32_16x16x32_bf16(tlo, bhi, acc3, 0, 0, 0);
        acc3 = __builtin_amdgcn_mfma_f32_16x16x32_bf16(thi, blo, acc3, 0, 0, 0);
      }
    }
    f32x4 accS = accA + accB;
    #pragma unroll
    for (int i = 0; i < 4; i++) {
      int m = wid * 16 + (lane >> 4) * 4 + i;
      int j = m & 31, ri = m >> 5;
      xf[((size_t)bc * 32 + j) * 32 + kx * 2 + ri] = accS[i];
    }
  }
  __syncthreads();

  if (t < 32) {
    float sum = 0.f;
    #pragma unroll
    for (int seg = 0; seg < 8; seg++) sum += cpart[seg][t];
    int b = bc >> 6, c = bc & 63;
    int f1 = t >> 3, f2 = (t >> 1) & 3, ri = t & 1;
    flat[(size_t)b * 2048 + ((c * 4 + f1) * 4 + f2) * 2 + ri] = sum;
  }
}

// ---------------- MLP (merged): flat -> corr, one block per b ----------------
__global__ __launch_bounds__(512) void k_mlp(const float* __restrict__ flat,
                                             const float* __restrict__ w1,
                                             const float* __restrict__ b1,
                                             const float* __restrict__ w2,
                                             const float* __restrict__ b2,
                                             float* __restrict__ corr) {
  __shared__ float part[2][256];
  __shared__ float hs[256];
  int b = blockIdx.x, t = threadIdx.x;
  int ol = t & 255, kc = t >> 8;         // 2-way k-split
  const float* fb = flat + (size_t)b * 2048 + kc * 1024;
  const float* wb = w1 + (size_t)(kc * 1024) * 256 + ol;
  float acc = 0.f;
  for (int k = 0; k < 1024; k++) acc = fmaf(fb[k], wb[(size_t)k * 256], acc);
  part[kc][ol] = acc;
  __syncthreads();
  if (t < 256) {
    float a = part[0][t] + part[1][t] + b1[t];
    hs[t] = 0.5f * a * (1.0f + erff(a * 0.70710678118654752f));
  }
  __syncthreads();
  if (t < 64) {
    float a2 = b2[t];
    for (int k = 0; k < 256; k++) a2 = fmaf(hs[k], w2[(size_t)k * 64 + t], a2);
    corr[(size_t)b * 64 + t] = a2;
  }
}

// ---------------- stage C: mode-mixing einsum over C ----------------
__global__ __launch_bounds__(256) void k_stageC(const float* __restrict__ xf,
                                                const float* __restrict__ w1,
                                                const float* __restrict__ w2,
                                                float* __restrict__ outft) {
  __shared__ float xfs[64 * 32];       // [c][kx*2+ri]
  int bid = blockIdx.x;
  int sw = (bid & 7) * 128 + (bid >> 3);   // bijective (1024 % 8 == 0)
  int j = sw >> 5, b = sw & 31;
  int t = threadIdx.x;
  #pragma unroll
  for (int k2 = 0; k2 < 4; k2++) {
    int id = t + k2 * 256;             // 1024 float2
    int c = id >> 4, kxi = id & 15;
    const float2 v = *reinterpret_cast<const float2*>(
        xf + (((size_t)b * 64 + c) * 32 + j) * 32 + kxi * 2);
    reinterpret_cast<float2*>(xfs)[id] = v;
  }
  __syncthreads();
  int kx = t & 15, og = t >> 4;
  const float* wsel = (j < 16) ? w1 : w2;
  int jr = (j < 16) ? j : j - 16;
  float aR[4], aI[4];
  #pragma unroll
  for (int i = 0; i < 4; i++) { aR[i] = 0.f; aI[i] = 0.f; }
  for (int c = 0; c < 64; c++) {
    float xr = xfs[c * 32 + kx * 2], xi = xfs[c * 32 + kx * 2 + 1];
    #pragma unroll
    for (int i = 0; i < 4; i++) {
      int o = og * 4 + i;
      const float2 wv = *reinterpret_cast<const float2*>(
          wsel + ((((size_t)c * 64 + o) * 16 + jr) * 16 + kx) * 2);
      aR[i] = fmaf(xr, wv.x, fmaf(-xi, wv.y, aR[i]));
      aI[i] = fmaf(xr, wv.y, fmaf(xi, wv.x, aI[i]));
    }
  }
  int boff = (j >> 4) * 512 + ((((j >> 2) & 3) << 4) | kx) * 8 + (j & 3) * 2;
  #pragma unroll
  for (int i = 0; i < 4; i++) {
    int o = og * 4 + i;
    float2* dst = reinterpret_cast<float2*>(outft + (size_t)(b * 64 + o) * 1024 + boff);
    *dst = make_float2(aR[i], aI[i]);
  }
}

// ---------------- stage DE: two chained split-bf16 MFMA GEMMs per (b,o) ----------------
// Round-15: GEMM1 emits PACKED split-bf16 Y into LDS (converted once); GEMM2's
// A-fragments are unpack-only (shift/and) — removes the per-wave re-conversion.
__global__ __launch_bounds__(256) void k_stageDE(const float* __restrict__ outft,
                                                 const float* __restrict__ corr,
                                                 float* __restrict__ out) {
  __shared__ unsigned Yp[256 * 17];    // [u*128+h][jj] packed (hi | lo<<16)
  int t = threadIdx.x;
  int lane = t & 63, wid = t >> 6;
  int bo = blockIdx.x;
  const float* src = outft + (size_t)bo * 1024;

  bf16x8 shi[2], slo[2];
  #pragma unroll
  for (int ks = 0; ks < 2; ks++) {
    float4 v0 = *reinterpret_cast<const float4*>(src + ks * 512 + lane * 8);
    float4 v1 = *reinterpret_cast<const float4*>(src + ks * 512 + lane * 8 + 4);
    float xv[8] = {v0.x, v0.y, v0.z, v0.w, v1.x, v1.y, v1.z, v1.w};
    ushort8 hu, lu;
    #pragma unroll
    for (int j = 0; j < 8; j++) {
      unsigned short h = f2bf(xv[j]);
      hu[j] = h;
      lu[j] = f2bf(xv[j] - bf2f(h));
    }
    shi[ks] = __builtin_bit_cast(bf16x8, hu);
    slo[ks] = __builtin_bit_cast(bf16x8, lu);
  }

  #pragma unroll
  for (int mtl = 0; mtl < 4; mtl++) {
    int mt = wid * 4 + mtl;
    f32x4 acc = {0.f, 0.f, 0.f, 0.f};
    #pragma unroll
    for (int ks = 0; ks < 2; ks++) {
      bf16x8 whi = __builtin_bit_cast(bf16x8,
          *reinterpret_cast<const ushort8*>(&g_w1tab.v[mt][ks][0][lane][0]));
      bf16x8 wlo = __builtin_bit_cast(bf16x8,
          *reinterpret_cast<const ushort8*>(&g_w1tab.v[mt][ks][1][lane][0]));
      acc = __builtin_amdgcn_mfma_f32_16x16x32_bf16(whi, shi[ks], acc, 0, 0, 0);
      acc = __builtin_amdgcn_mfma_f32_16x16x32_bf16(wlo, shi[ks], acc, 0, 0, 0);
      acc = __builtin_amdgcn_mfma_f32_16x16x32_bf16(whi, slo[ks], acc, 0, 0, 0);
    }
    #pragma unroll
    for (int i = 0; i < 4; i++) {
      float v = acc[i];
      unsigned short hi = f2bf(v);
      unsigned short lo = f2bf(v - bf2f(hi));
      Yp[(mt * 16 + (lane >> 4) * 4 + i) * 17 + (lane & 15)] =
          ((unsigned)lo << 16) | (unsigned)hi;
    }
  }
  __syncthreads();

  float corrv = corr[bo];
  float* obase = out + (size_t)bo * 16384;

  #pragma unroll
  for (int mtl = 0; mtl < 2; mtl++) {
    int mt2 = wid * 2 + mtl;
    int h = mt2 * 16 + (lane & 15);
    int g = lane >> 4;
    ushort8 ahiU, aloU;
    #pragma unroll
    for (int j = 0; j < 8; j++) {
      int k = g * 8 + j;
      unsigned p = Yp[((k & 1) * 128 + h) * 17 + (k >> 1)];
      ahiU[j] = (unsigned short)(p & 0xFFFFu);
      aloU[j] = (unsigned short)(p >> 16);
    }
    bf16x8 ahi = __builtin_bit_cast(bf16x8, ahiU);
    bf16x8 alo = __builtin_bit_cast(bf16x8, aloU);
    #pragma unroll
    for (int nt = 0; nt < 8; nt++) {
      bf16x8 bhi = __builtin_bit_cast(bf16x8,
          *reinterpret_cast<const ushort8*>(&g_w2tab.v[nt][0][lane][0]));
      bf16x8 blo = __builtin_bit_cast(bf16x8,
          *reinterpret_cast<const ushort8*>(&g_w2tab.v[nt][1][lane][0]));
      f32x4 acc = {corrv, corrv, corrv, corrv};
      acc = __builtin_amdgcn_mfma_f32_16x16x32_bf16(ahi, bhi, acc, 0, 0, 0);
      acc = __builtin_amdgcn_mfma_f32_16x16x32_bf16(alo, bhi, acc, 0, 0, 0);
      acc = __builtin_amdgcn_mfma_f32_16x16x32_bf16(ahi, blo, acc, 0, 0, 0);
      #pragma unroll
      for (int i = 0; i < 4; i++)
        obase[(mt2 * 16 + (lane >> 4) * 4 + i) * 128 + nt * 16 + (lane & 15)] = acc[i];
    }
  }
}

extern "C" void kernel_launch(void* const* d_in, const int* in_sizes, int n_in,
                              void* d_out, int out_size, void* d_ws, size_t ws_size,
                              hipStream_t stream) {
  const float* x   = (const float*)d_in[0];
  const float* w1  = (const float*)d_in[1];
  const float* w2  = (const float*)d_in[2];
  const float* l1w = (const float*)d_in[3];
  const float* l1b = (const float*)d_in[4];
  const float* l2w = (const float*)d_in[5];
  const float* l2b = (const float*)d_in[6];
  float* out = (float*)d_out;
  float* ws  = (float*)d_ws;

  float* flat  = ws + WSO_FLAT;
  float* corr  = ws + WSO_CORR;
  float* xf    = ws + WSO_XF;
  float* outft = ws + WSO_OUTFT;

  k_fwd<<<dim3(2048), dim3(256), 0, stream>>>(x, xf, flat);
  k_mlp<<<dim3(32), dim3(512), 0, stream>>>(flat, l1w, l1b, l2w, l2b, corr);
  k_stageC<<<dim3(1024), dim3(256), 0, stream>>>(xf, w1, w2, outft);
  k_stageDE<<<dim3(2048), dim3(256), 0, stream>>>(outft, corr, out);
}

// Round 16
// 126.916 us; speedup vs baseline: 1.2483x; 1.2483x over previous
//
#include <hip/hip_runtime.h>
#include <math.h>

#define PI_F 3.14159265358979323846f
#define TWO_PI_F 6.28318530717958647692f

// problem sizes
constexpr int Bn = 32, Cn = 64, On = 64, Hn = 128, Wn = 128;

// workspace float offsets (small region < WSO_BIG)
constexpr size_t WSO_FLAT  = 0;                        // 32*2048 = 65536
constexpr size_t WSO_CORR  = 65536;                    // 32*64   = 2048
constexpr size_t WSO_HS    = 67584;                    // 32*256  = 8192
constexpr size_t WSO_BIG   = 81920;
constexpr size_t SZ_QTR    = (size_t)2097152;          // 2M floats
constexpr size_t WSO_XF    = WSO_BIG + SZ_QTR;         // [2048][32][16][2]
constexpr size_t WSO_OUTFT = WSO_BIG + 4 * SZ_QTR;     // [2048][1024] B-frag order

// ================= compile-time tables =================
struct Tabs {
  float ktw[128][40];
  float cfth[128][8];
};

constexpr double D_PI = 3.14159265358979323846;

constexpr double d_red(double x) {
  while (x >  D_PI) x -= 2.0 * D_PI;
  while (x < -D_PI) x += 2.0 * D_PI;
  return x;
}
constexpr double d_sin(double x) {
  x = d_red(x);
  double x2 = x * x, t = x, s = x;
  for (int n = 1; n <= 10; n++) { t *= -x2 / (double)((2 * n) * (2 * n + 1)); s += t; }
  return s;
}
constexpr double d_cos(double x) {
  x = d_red(x);
  double x2 = x * x, t = 1.0, s = 1.0;
  for (int n = 1; n <= 10; n++) { t *= -x2 / (double)((2 * n - 1) * (2 * n)); s += t; }
  return s;
}

constexpr Tabs make_tabs() {
  Tabs T{};
  double twc[128] = {}, tws[128] = {};
  for (int r = 0; r < 128; r++) {
    double a = 2.0 * D_PI * (double)r / 128.0;
    twc[r] = d_cos(a); tws[r] = d_sin(a);
  }
  for (int kx = 0; kx < 16; kx++)
    for (int w = 0; w < 128; w++) {
      int r = (kx * w) & 127;
      T.ktw[w][2 * kx]     = (float)twc[r];
      T.ktw[w][2 * kx + 1] = (float)(-tws[r]);
    }
  double node[8] = {}, theta[8] = {};
  for (int m = 0; m < 8; m++) { theta[m] = (2.0 * m + 1.0) * D_PI / 16.0; node[m] = -d_cos(theta[m]); }
  double Tch[8][8] = {};
  for (int k = 0; k < 8; k++)
    for (int m = 0; m < 8; m++) Tch[k][m] = d_cos((double)k * (D_PI - theta[m]));
  int LE[4][8] = {}, RI[4][8] = {};
  float WL[4][8] = {}, WR[4][8] = {};
  for (int l = 0; l < 4; l++)
    for (int m = 0; m < 8; m++) {
      float tseg = (float)(0.25 * (double)l + 0.125 * (node[m] + 1.0));
      int ri = (int)(tseg * 127.0f) - 2; if (ri < 0) ri = 0;
      while (ri < 127 && ((float)ri * (1.0f / 127.0f)) < tseg) ri++;
      int le = ri - 1; if (le < 0) le = 0;
      float tl = (float)le * (1.0f / 127.0f), tr = (float)ri * (1.0f / 127.0f);
      float den = (tr - tl < 1e-8f) ? 1.0f : (tr - tl);
      float wr = (tseg - tl) / den;
      LE[l][m] = le; RI[l][m] = ri; WR[l][m] = wr; WL[l][m] = 1.0f - wr;
    }
  for (int p = 0; p < 2; p++)
    for (int f = 0; f < 4; f++) {
      double fval = (p == 0) ? (double)f
                             : ((f == 0) ? 0.0 : (f == 1) ? 1.0 : (f == 2) ? -2.0 : -1.0);
      double wp = fval * (2.0 * D_PI * 0.125);
      double Wr[8] = {}, Wi[8] = {};
      for (int k = 0; k < 8; k++) {
        double sr = 0.0, si = 0.0;
        for (int m = 0; m < 8; m++) {
          sr += Tch[k][m] * d_cos(node[m] * wp);
          si += Tch[k][m] * (-d_sin(node[m] * wp));
        }
        Wr[k] = sr * 0.125; Wi[k] = si * 0.125;
      }
      for (int l = 0; l < 4; l++) {
        double ph = -2.0 * D_PI * (0.25 * (double)l) * fval;
        double cr = d_cos(ph), ci = d_sin(ph);
        for (int m = 0; m < 8; m++) {
          double coefR = Wr[m] * cr - Wi[m] * ci;
          double coefI = Wr[m] * ci + Wi[m] * cr;
          int le = LE[l][m], ri = RI[l][m];
          if (p == 0) {
            T.ktw[le][32 + f] += (float)(WL[l][m] * coefR);
            T.ktw[le][36 + f] += (float)(WL[l][m] * coefI);
            T.ktw[ri][32 + f] += (float)(WR[l][m] * coefR);
            T.ktw[ri][36 + f] += (float)(WR[l][m] * coefI);
          } else {
            T.cfth[le][f]     += (float)(WL[l][m] * coefR);
            T.cfth[le][4 + f] += (float)(WL[l][m] * coefI);
            T.cfth[ri][f]     += (float)(WR[l][m] * coefR);
            T.cfth[ri][4 + f] += (float)(WR[l][m] * coefI);
          }
        }
      }
    }
  return T;
}

// ---- bf16 split helpers: compile-time (bit-trick RNE) ----
constexpr unsigned short cf2bf(float f) {
  unsigned u = __builtin_bit_cast(unsigned, f);
  u += 0x7FFFu + ((u >> 16) & 1u);
  return (unsigned short)(u >> 16);
}
constexpr float cbf2f(unsigned short h) {
  return __builtin_bit_cast(float, (unsigned)h << 16);
}

// -------- cfth coefficient table (f32) --------
struct CfthT { float v[128][8]; };
constexpr CfthT make_cfth() {
  CfthT C{};
  Tabs T = make_tabs();
  for (int h = 0; h < 128; h++)
    for (int q = 0; q < 8; q++) C.v[h][q] = T.cfth[h][q];
  return C;
}
__constant__ CfthT g_cfth = make_cfth();

// -------- stage A B-table --------
struct alignas(16) BTab {
  unsigned short v[4][2][3][64][8];   // [kstep][hi/lo][jtile][lane][j]
};
constexpr BTab make_btab() {
  BTab B{};
  Tabs T = make_tabs();
  for (int ks = 0; ks < 4; ks++)
    for (int jt = 0; jt < 3; jt++)
      for (int lane = 0; lane < 64; lane++)
        for (int j = 0; j < 8; j++) {
          int col = jt * 16 + (lane & 15);
          int k = ks * 32 + (lane >> 4) * 8 + j;
          float val = (col < 40) ? T.ktw[k][col] : 0.0f;
          unsigned short h = cf2bf(val);
          B.v[ks][0][jt][lane][j] = h;
          B.v[ks][1][jt][lane][j] = cf2bf(val - cbf2f(h));
        }
  return B;
}
__constant__ BTab g_btab = make_btab();

// -------- fwd B-part A-table: TB[64 m=(ri*32+j)][256 k=(2h+u)] --------
struct alignas(16) TBTab {
  unsigned short v[4][8][2][64][8];   // [mtile][kstep][hi/lo][lane][j]
};
constexpr TBTab make_tbtab() {
  TBTab T{};
  double twc[128] = {}, tws[128] = {};
  for (int r = 0; r < 128; r++) {
    double a = 2.0 * D_PI * (double)r / 128.0;
    twc[r] = d_cos(a); tws[r] = d_sin(a);
  }
  for (int mt = 0; mt < 4; mt++)
    for (int ks = 0; ks < 8; ks++)
      for (int lane = 0; lane < 64; lane++)
        for (int js = 0; js < 8; js++) {
          int m = mt * 16 + (lane & 15);
          int j = m & 31, ri = m >> 5;
          int k = ks * 32 + (lane >> 4) * 8 + js;
          int h = k >> 1, u = k & 1;
          int ky = (j < 16) ? j : j + 96;
          int idx = (ky * h) & 127;
          double c = twc[idx], s = tws[idx];
          double val = (ri == 0) ? ((u == 0) ? c : s)
                                 : ((u == 0) ? -s : c);
          float f = (float)val;
          unsigned short hi = cf2bf(f);
          T.v[mt][ks][0][lane][js] = hi;
          T.v[mt][ks][1][lane][js] = cf2bf(f - cbf2f(hi));
        }
  return T;
}
__constant__ TBTab g_tbtab = make_tbtab();

// -------- stage DE GEMM1 A-table --------
struct alignas(16) W1Tab {
  unsigned short v[16][2][2][64][8];  // [mtile][kstep][hi/lo][lane][j]
};
constexpr W1Tab make_w1tab() {
  W1Tab T{};
  double twc[128] = {}, tws[128] = {};
  for (int r = 0; r < 128; r++) {
    double a = 2.0 * D_PI * (double)r / 128.0;
    twc[r] = d_cos(a); tws[r] = d_sin(a);
  }
  for (int mt = 0; mt < 16; mt++)
    for (int ks = 0; ks < 2; ks++)
      for (int lane = 0; lane < 64; lane++)
        for (int j = 0; j < 8; j++) {
          int r = mt * 16 + (lane & 15);
          int k = ks * 32 + (lane >> 4) * 8 + j;
          int jj = k >> 1, u = k & 1;
          int ky = (jj < 16) ? jj : jj + 96;
          int h = r & 127;
          int idx = (ky * h) & 127;
          double c = twc[idx], s = tws[idx];
          double val = (r < 128) ? ((u == 0) ? c : -s)
                                 : ((u == 0) ? s : c);
          float f = (float)(val * (1.0 / 128.0));
          unsigned short hi = cf2bf(f);
          T.v[mt][ks][0][lane][j] = hi;
          T.v[mt][ks][1][lane][j] = cf2bf(f - cbf2f(hi));
        }
  return T;
}
__constant__ W1Tab g_w1tab = make_w1tab();

// -------- stage DE GEMM2 B-table --------
struct alignas(16) W2Tab {
  unsigned short v[8][2][64][8];      // [ntile][hi/lo][lane][j]
};
constexpr W2Tab make_w2tab() {
  W2Tab T{};
  double twc[128] = {}, tws[128] = {};
  for (int r = 0; r < 128; r++) {
    double a = 2.0 * D_PI * (double)r / 128.0;
    twc[r] = d_cos(a); tws[r] = d_sin(a);
  }
  for (int nt = 0; nt < 8; nt++)
    for (int lane = 0; lane < 64; lane++)
      for (int j = 0; j < 8; j++) {
        int w = nt * 16 + (lane & 15);
        int k = (lane >> 4) * 8 + j;
        int kx = k >> 1, u = k & 1;
        double val;
        if (kx == 0) val = (u == 0) ? 1.0 : 0.0;
        else {
          int idx = (kx * w) & 127;
          val = (u == 0) ? 2.0 * twc[idx] : -2.0 * tws[idx];
        }
        float f = (float)(val * (1.0 / 128.0));
        unsigned short hi = cf2bf(f);
        T.v[nt][0][lane][j] = hi;
        T.v[nt][1][lane][j] = cf2bf(f - cbf2f(hi));
      }
  return T;
}
__constant__ W2Tab g_w2tab = make_w2tab();

typedef __attribute__((ext_vector_type(8))) __bf16 bf16x8;
typedef __attribute__((ext_vector_type(8))) unsigned short ushort8;
typedef __attribute__((ext_vector_type(4))) float f32x4;

// ---- runtime bf16 helpers: native casts (v_cvt RNE) ----
__device__ __forceinline__ unsigned short f2bf(float f) {
  return __builtin_bit_cast(unsigned short, (__bf16)f);
}
__device__ __forceinline__ float bf2f(unsigned short h) {
  return (float)__builtin_bit_cast(__bf16, h);
}

// ---------------- fwd: fused stage A + stage B + CFT H-pass (round-12 best form) ----------------
__global__ __launch_bounds__(256) void k_fwd(const float* __restrict__ x,
                                             float* __restrict__ xf,
                                             float* __restrict__ flat) {
  __shared__ unsigned xwlp[128][34];   // [h][j=2kx+u] packed (hi | lo<<16)
  __shared__ float cftl[128][9];
  __shared__ float cpart[8][33];
  int t = threadIdx.x;
  int lane = t & 63, wid = t >> 6;
  int bc = blockIdx.x;
  const float* xb = x + (size_t)bc * 16384;
  int r = lane & 15, kg = lane >> 4;
  const float* a0 = xb + (wid * 32 + r) * 128 + kg * 8;
  const float* a1 = a0 + 16 * 128;

  float4 xa[16];
  #pragma unroll
  for (int ks = 0; ks < 4; ks++) {
    xa[2 * ks]     = *reinterpret_cast<const float4*>(a0 + ks * 32);
    xa[2 * ks + 1] = *reinterpret_cast<const float4*>(a0 + ks * 32 + 4);
  }
  #pragma unroll
  for (int ks = 0; ks < 4; ks++) {
    xa[8 + 2 * ks]     = *reinterpret_cast<const float4*>(a1 + ks * 32);
    xa[8 + 2 * ks + 1] = *reinterpret_cast<const float4*>(a1 + ks * 32 + 4);
  }

  bf16x8 ahi[2][4], alo[2][4];
  #pragma unroll
  for (int tl = 0; tl < 2; tl++) {
    #pragma unroll
    for (int ks = 0; ks < 4; ks++) {
      const float* p0 = reinterpret_cast<const float*>(&xa[tl * 8 + 2 * ks]);
      const float* p1 = reinterpret_cast<const float*>(&xa[tl * 8 + 2 * ks + 1]);
      ushort8 hu, lu;
      #pragma unroll
      for (int j = 0; j < 8; j++) {
        float v = (j < 4) ? p0[j] : p1[j - 4];
        unsigned short h = f2bf(v);
        hu[j] = h;
        lu[j] = f2bf(v - bf2f(h));
      }
      ahi[tl][ks] = __builtin_bit_cast(bf16x8, hu);
      alo[tl][ks] = __builtin_bit_cast(bf16x8, lu);
    }
  }

  f32x4 acc[2][3];
  #pragma unroll
  for (int tl = 0; tl < 2; tl++)
    #pragma unroll
    for (int jt = 0; jt < 3; jt++) acc[tl][jt] = f32x4{0.f, 0.f, 0.f, 0.f};
  #pragma unroll
  for (int jt = 0; jt < 3; jt++) {
    #pragma unroll
    for (int ks = 0; ks < 4; ks++) {
      bf16x8 bhi = __builtin_bit_cast(bf16x8,
          *reinterpret_cast<const ushort8*>(&g_btab.v[ks][0][jt][lane][0]));
      bf16x8 blo = __builtin_bit_cast(bf16x8,
          *reinterpret_cast<const ushort8*>(&g_btab.v[ks][1][jt][lane][0]));
      acc[0][jt] = __builtin_amdgcn_mfma_f32_16x16x32_bf16(ahi[0][ks], bhi, acc[0][jt], 0, 0, 0);
      acc[1][jt] = __builtin_amdgcn_mfma_f32_16x16x32_bf16(ahi[1][ks], bhi, acc[1][jt], 0, 0, 0);
      acc[0][jt] = __builtin_amdgcn_mfma_f32_16x16x32_bf16(alo[0][ks], bhi, acc[0][jt], 0, 0, 0);
      acc[1][jt] = __builtin_amdgcn_mfma_f32_16x16x32_bf16(alo[1][ks], bhi, acc[1][jt], 0, 0, 0);
      acc[0][jt] = __builtin_amdgcn_mfma_f32_16x16x32_bf16(ahi[0][ks], blo, acc[0][jt], 0, 0, 0);
      acc[1][jt] = __builtin_amdgcn_mfma_f32_16x16x32_bf16(ahi[1][ks], blo, acc[1][jt], 0, 0, 0);
    }
  }
  {
    int col = lane & 15, rq = lane >> 4;
    #pragma unroll
    for (int tl = 0; tl < 2; tl++) {
      int rt = wid * 2 + tl;
      #pragma unroll
      for (int jt = 0; jt < 3; jt++) {
        #pragma unroll
        for (int i = 0; i < 4; i++) {
          int rl = rt * 16 + rq * 4 + i;
          float v = acc[tl][jt][i];
          if (jt < 2) {
            unsigned short hi = f2bf(v);
            unsigned short lo = f2bf(v - bf2f(hi));
            xwlp[rl][jt * 16 + col] = ((unsigned)lo << 16) | (unsigned)hi;
          } else if (col < 8) {
            cftl[rl][col] = v;
          }
        }
      }
    }
  }
  __syncthreads();

  {
    int o = t & 31, seg = t >> 5;
    int f1 = o >> 3, f2 = (o >> 1) & 3, ri = o & 1;
    float acc2 = 0.f;
    #pragma unroll
    for (int hh = 0; hh < 16; hh++) {
      int h = seg * 16 + hh;
      float rr = cftl[h][f2], im = cftl[h][4 + f2];
      float kr = g_cfth.v[h][f1], ki = g_cfth.v[h][4 + f1];
      float e0 = ri ? ki : kr;
      float e1 = ri ? kr : -ki;
      acc2 = fmaf(rr, e0, fmaf(im, e1, acc2));
    }
    cpart[seg][o] = acc2;
  }

  {
    int kx = lane & 15, g = lane >> 4;
    f32x4 accA = {0.f, 0.f, 0.f, 0.f};
    f32x4 accB = {0.f, 0.f, 0.f, 0.f};
    #pragma unroll
    for (int ks2 = 0; ks2 < 4; ks2++) {
      #pragma unroll
      for (int half = 0; half < 2; half++) {
        int ks = half * 4 + ks2;
        int h0 = ks * 16 + g * 4;
        ushort8 bhU, blU;
        #pragma unroll
        for (int rr = 0; rr < 4; rr++) {
          uint2 p = *reinterpret_cast<const uint2*>(&xwlp[h0 + rr][2 * kx]);
          bhU[2 * rr]     = (unsigned short)(p.x & 0xFFFFu);
          blU[2 * rr]     = (unsigned short)(p.x >> 16);
          bhU[2 * rr + 1] = (unsigned short)(p.y & 0xFFFFu);
          blU[2 * rr + 1] = (unsigned short)(p.y >> 16);
        }
        bf16x8 bhi = __builtin_bit_cast(bf16x8, bhU);
        bf16x8 blo = __builtin_bit_cast(bf16x8, blU);
        bf16x8 thi = __builtin_bit_cast(bf16x8,
            *reinterpret_cast<const ushort8*>(&g_tbtab.v[wid][ks][0][lane][0]));
        bf16x8 tlo = __builtin_bit_cast(bf16x8,
            *reinterpret_cast<const ushort8*>(&g_tbtab.v[wid][ks][1][lane][0]));
        f32x4& acc3 = half ? accB : accA;
        acc3 = __builtin_amdgcn_mfma_f32_16x16x32_bf16(thi, bhi, acc3, 0, 0, 0);
        acc3 = __builtin_amdgcn_mfma_f32_16x16x32_bf16(tlo, bhi, acc3, 0, 0, 0);
        acc3 = __builtin_amdgcn_mfma_f32_16x16x32_bf16(thi, blo, acc3, 0, 0, 0);
      }
    }
    f32x4 accS = accA + accB;
    #pragma unroll
    for (int i = 0; i < 4; i++) {
      int m = wid * 16 + (lane >> 4) * 4 + i;
      int j = m & 31, ri = m >> 5;
      xf[((size_t)bc * 32 + j) * 32 + kx * 2 + ri] = accS[i];
    }
  }
  __syncthreads();

  if (t < 32) {
    float sum = 0.f;
    #pragma unroll
    for (int seg = 0; seg < 8; seg++) sum += cpart[seg][t];
    int b = bc >> 6, c = bc & 63;
    int f1 = t >> 3, f2 = (t >> 1) & 3, ri = t & 1;
    flat[(size_t)b * 2048 + ((c * 4 + f1) * 4 + f2) * 2 + ri] = sum;
  }
}

// ---------------- MLP stage 1: flat -> hs ----------------
__global__ __launch_bounds__(256) void k_mlp1(const float* __restrict__ flat,
                                              const float* __restrict__ w1,
                                              const float* __restrict__ b1,
                                              float* __restrict__ hs) {
  __shared__ float part[4][64];
  int bid = blockIdx.x;
  int b = bid >> 2, oc = bid & 3;
  int t = threadIdx.x;
  int ol = t & 63, kc = t >> 6;
  int o = oc * 64 + ol;
  const float* fb = flat + (size_t)b * 2048 + kc * 512;
  const float* wb = w1 + (size_t)(kc * 512) * 256 + o;
  float acc = 0.f;
  for (int k = 0; k < 512; k++) acc = fmaf(fb[k], wb[(size_t)k * 256], acc);
  part[kc][ol] = acc;
  __syncthreads();
  if (t < 64) {
    float a = part[0][t] + part[1][t] + part[2][t] + part[3][t] + b1[oc * 64 + t];
    hs[(size_t)b * 256 + oc * 64 + t] = 0.5f * a * (1.0f + erff(a * 0.70710678118654752f));
  }
}

// ---------------- MLP stage 2: hs -> corr ----------------
__global__ void k_mlp2(const float* __restrict__ hs,
                       const float* __restrict__ w2,
                       const float* __restrict__ b2,
                       float* __restrict__ corr) {
  int b = blockIdx.x, t = threadIdx.x;   // 64 threads
  const float* hb = hs + (size_t)b * 256;
  float acc = b2[t];
  for (int k = 0; k < 256; k++) acc = fmaf(hb[k], w2[(size_t)k * 64 + t], acc);
  corr[(size_t)b * 64 + t] = acc;
}

// ---------------- stage C: mode-mixing einsum over C, 4 b's per block ----------------
// Round-16: grid 256 = (j, bq). Each block stages xf for 4 b's and reuses every
// w load across them (w traffic 537 -> 134 MB). XCD map: all 8 blocks of a j
// (and 4 j's) land on one XCD -> w slice L2-resident. Same math/layout as before.
__global__ __launch_bounds__(256) void k_stageC(const float* __restrict__ xf,
                                                const float* __restrict__ w1,
                                                const float* __restrict__ w2,
                                                float* __restrict__ outft) {
  __shared__ float xfs[4][2048];       // [bb][c*32 + kx*2+u]
  int bid = blockIdx.x;
  int xcd = bid & 7, kk = bid >> 3;    // kk 0..31
  int j = xcd * 4 + (kk & 3);
  int bq = kk >> 2;                    // 0..7
  int b0 = bq * 4;
  int t = threadIdx.x;

  #pragma unroll
  for (int bb = 0; bb < 4; bb++) {
    int b = b0 + bb;
    #pragma unroll
    for (int k2 = 0; k2 < 4; k2++) {
      int id = t + k2 * 256;           // 1024 float2 per b
      int c = id >> 4, kxi = id & 15;
      const float2 v = *reinterpret_cast<const float2*>(
          xf + (((size_t)b * 64 + c) * 32 + j) * 32 + kxi * 2);
      reinterpret_cast<float2*>(&xfs[bb][0])[id] = v;
    }
  }
  __syncthreads();

  int kx = t & 15, og = t >> 4;
  const float* wsel = (j < 16) ? w1 : w2;
  int jr = (j < 16) ? j : j - 16;
  float aR[4][4], aI[4][4];            // [bb][i]
  #pragma unroll
  for (int bb = 0; bb < 4; bb++)
    #pragma unroll
    for (int i = 0; i < 4; i++) { aR[bb][i] = 0.f; aI[bb][i] = 0.f; }

  for (int c = 0; c < 64; c++) {
    float2 wv[4];
    #pragma unroll
    for (int i = 0; i < 4; i++) {
      int o = og * 4 + i;
      wv[i] = *reinterpret_cast<const float2*>(
          wsel + ((((size_t)c * 64 + o) * 16 + jr) * 16 + kx) * 2);
    }
    #pragma unroll
    for (int bb = 0; bb < 4; bb++) {
      float xr = xfs[bb][c * 32 + kx * 2], xi = xfs[bb][c * 32 + kx * 2 + 1];
      #pragma unroll
      for (int i = 0; i < 4; i++) {
        aR[bb][i] = fmaf(xr, wv[i].x, fmaf(-xi, wv[i].y, aR[bb][i]));
        aI[bb][i] = fmaf(xr, wv[i].y, fmaf(xi, wv[i].x, aI[bb][i]));
      }
    }
  }

  int boff = (j >> 4) * 512 + ((((j >> 2) & 3) << 4) | kx) * 8 + (j & 3) * 2;
  #pragma unroll
  for (int bb = 0; bb < 4; bb++) {
    int b = b0 + bb;
    #pragma unroll
    for (int i = 0; i < 4; i++) {
      int o = og * 4 + i;
      float2* dst = reinterpret_cast<float2*>(outft + (size_t)(b * 64 + o) * 1024 + boff);
      *dst = make_float2(aR[bb][i], aI[bb][i]);
    }
  }
}

// ---------------- stage DE: two chained split-bf16 MFMA GEMMs per (b,o) ----------------
__global__ __launch_bounds__(256) void k_stageDE(const float* __restrict__ outft,
                                                 const float* __restrict__ corr,
                                                 float* __restrict__ out) {
  __shared__ float Yl[256 * 17];
  int t = threadIdx.x;
  int lane = t & 63, wid = t >> 6;
  int bo = blockIdx.x;
  const float* src = outft + (size_t)bo * 1024;

  bf16x8 shi[2], slo[2];
  #pragma unroll
  for (int ks = 0; ks < 2; ks++) {
    float4 v0 = *reinterpret_cast<const float4*>(src + ks * 512 + lane * 8);
    float4 v1 = *reinterpret_cast<const float4*>(src + ks * 512 + lane * 8 + 4);
    float xv[8] = {v0.x, v0.y, v0.z, v0.w, v1.x, v1.y, v1.z, v1.w};
    ushort8 hu, lu;
    #pragma unroll
    for (int j = 0; j < 8; j++) {
      unsigned short h = f2bf(xv[j]);
      hu[j] = h;
      lu[j] = f2bf(xv[j] - bf2f(h));
    }
    shi[ks] = __builtin_bit_cast(bf16x8, hu);
    slo[ks] = __builtin_bit_cast(bf16x8, lu);
  }

  #pragma unroll
  for (int mtl = 0; mtl < 4; mtl++) {
    int mt = wid * 4 + mtl;
    f32x4 acc = {0.f, 0.f, 0.f, 0.f};
    #pragma unroll
    for (int ks = 0; ks < 2; ks++) {
      bf16x8 whi = __builtin_bit_cast(bf16x8,
          *reinterpret_cast<const ushort8*>(&g_w1tab.v[mt][ks][0][lane][0]));
      bf16x8 wlo = __builtin_bit_cast(bf16x8,
          *reinterpret_cast<const ushort8*>(&g_w1tab.v[mt][ks][1][lane][0]));
      acc = __builtin_amdgcn_mfma_f32_16x16x32_bf16(whi, shi[ks], acc, 0, 0, 0);
      acc = __builtin_amdgcn_mfma_f32_16x16x32_bf16(wlo, shi[ks], acc, 0, 0, 0);
      acc = __builtin_amdgcn_mfma_f32_16x16x32_bf16(whi, slo[ks], acc, 0, 0, 0);
    }
    #pragma unroll
    for (int i = 0; i < 4; i++)
      Yl[(mt * 16 + (lane >> 4) * 4 + i) * 17 + (lane & 15)] = acc[i];
  }
  __syncthreads();

  float corrv = corr[bo];
  float* obase = out + (size_t)bo * 16384;

  #pragma unroll
  for (int mtl = 0; mtl < 2; mtl++) {
    int mt2 = wid * 2 + mtl;
    int h = mt2 * 16 + (lane & 15);
    ushort8 ahiU, aloU;
    #pragma unroll
    for (int j = 0; j < 8; j++) {
      int k = (lane >> 4) * 8 + j;
      float v = Yl[((k & 1) * 128 + h) * 17 + (k >> 1)];
      unsigned short hi = f2bf(v);
      ahiU[j] = hi;
      aloU[j] = f2bf(v - bf2f(hi));
    }
    bf16x8 ahi = __builtin_bit_cast(bf16x8, ahiU);
    bf16x8 alo = __builtin_bit_cast(bf16x8, aloU);
    #pragma unroll
    for (int nt = 0; nt < 8; nt++) {
      bf16x8 bhi = __builtin_bit_cast(bf16x8,
          *reinterpret_cast<const ushort8*>(&g_w2tab.v[nt][0][lane][0]));
      bf16x8 blo = __builtin_bit_cast(bf16x8,
          *reinterpret_cast<const ushort8*>(&g_w2tab.v[nt][1][lane][0]));
      f32x4 acc = {corrv, corrv, corrv, corrv};
      acc = __builtin_amdgcn_mfma_f32_16x16x32_bf16(ahi, bhi, acc, 0, 0, 0);
      acc = __builtin_amdgcn_mfma_f32_16x16x32_bf16(alo, bhi, acc, 0, 0, 0);
      acc = __builtin_amdgcn_mfma_f32_16x16x32_bf16(ahi, blo, acc, 0, 0, 0);
      #pragma unroll
      for (int i = 0; i < 4; i++)
        obase[(mt2 * 16 + (lane >> 4) * 4 + i) * 128 + nt * 16 + (lane & 15)] = acc[i];
    }
  }
}

extern "C" void kernel_launch(void* const* d_in, const int* in_sizes, int n_in,
                              void* d_out, int out_size, void* d_ws, size_t ws_size,
                              hipStream_t stream) {
  const float* x   = (const float*)d_in[0];
  const float* w1  = (const float*)d_in[1];
  const float* w2  = (const float*)d_in[2];
  const float* l1w = (const float*)d_in[3];
  const float* l1b = (const float*)d_in[4];
  const float* l2w = (const float*)d_in[5];
  const float* l2b = (const float*)d_in[6];
  float* out = (float*)d_out;
  float* ws  = (float*)d_ws;

  float* flat  = ws + WSO_FLAT;
  float* corr  = ws + WSO_CORR;
  float* hs    = ws + WSO_HS;
  float* xf    = ws + WSO_XF;
  float* outft = ws + WSO_OUTFT;

  k_fwd<<<dim3(2048), dim3(256), 0, stream>>>(x, xf, flat);
  k_mlp1<<<dim3(128), dim3(256), 0, stream>>>(flat, l1w, l1b, hs);
  k_mlp2<<<dim3(32), dim3(64), 0, stream>>>(hs, l2w, l2b, corr);
  k_stageC<<<dim3(256), dim3(256), 0, stream>>>(xf, w1, w2, outft);
  k_stageDE<<<dim3(2048), dim3(256), 0, stream>>>(outft, corr, out);
}

// Round 17
// 126.087 us; speedup vs baseline: 1.2565x; 1.0066x over previous
//
#include <hip/hip_runtime.h>
#include <math.h>

#define PI_F 3.14159265358979323846f
#define TWO_PI_F 6.28318530717958647692f

// problem sizes
constexpr int Bn = 32, Cn = 64, On = 64, Hn = 128, Wn = 128;

// workspace float offsets (small region < WSO_BIG)
constexpr size_t WSO_FLAT  = 0;                        // 32*2048 = 65536
constexpr size_t WSO_CORR  = 65536;                    // 32*64   = 2048
constexpr size_t WSO_HS    = 67584;                    // 32*256  = 8192
constexpr size_t WSO_BIG   = 81920;
constexpr size_t SZ_QTR    = (size_t)2097152;          // 2M floats
constexpr size_t WSO_XF    = WSO_BIG + SZ_QTR;         // [2048][32][16][2]
constexpr size_t WSO_OUTFT = WSO_BIG + 4 * SZ_QTR;     // [2048][1024] B-frag order

// ================= compile-time tables =================
struct Tabs {
  float ktw[128][40];
  float cfth[128][8];
};

constexpr double D_PI = 3.14159265358979323846;

constexpr double d_red(double x) {
  while (x >  D_PI) x -= 2.0 * D_PI;
  while (x < -D_PI) x += 2.0 * D_PI;
  return x;
}
constexpr double d_sin(double x) {
  x = d_red(x);
  double x2 = x * x, t = x, s = x;
  for (int n = 1; n <= 10; n++) { t *= -x2 / (double)((2 * n) * (2 * n + 1)); s += t; }
  return s;
}
constexpr double d_cos(double x) {
  x = d_red(x);
  double x2 = x * x, t = 1.0, s = 1.0;
  for (int n = 1; n <= 10; n++) { t *= -x2 / (double)((2 * n - 1) * (2 * n)); s += t; }
  return s;
}

constexpr Tabs make_tabs() {
  Tabs T{};
  double twc[128] = {}, tws[128] = {};
  for (int r = 0; r < 128; r++) {
    double a = 2.0 * D_PI * (double)r / 128.0;
    twc[r] = d_cos(a); tws[r] = d_sin(a);
  }
  for (int kx = 0; kx < 16; kx++)
    for (int w = 0; w < 128; w++) {
      int r = (kx * w) & 127;
      T.ktw[w][2 * kx]     = (float)twc[r];
      T.ktw[w][2 * kx + 1] = (float)(-tws[r]);
    }
  double node[8] = {}, theta[8] = {};
  for (int m = 0; m < 8; m++) { theta[m] = (2.0 * m + 1.0) * D_PI / 16.0; node[m] = -d_cos(theta[m]); }
  double Tch[8][8] = {};
  for (int k = 0; k < 8; k++)
    for (int m = 0; m < 8; m++) Tch[k][m] = d_cos((double)k * (D_PI - theta[m]));
  int LE[4][8] = {}, RI[4][8] = {};
  float WL[4][8] = {}, WR[4][8] = {};
  for (int l = 0; l < 4; l++)
    for (int m = 0; m < 8; m++) {
      float tseg = (float)(0.25 * (double)l + 0.125 * (node[m] + 1.0));
      int ri = (int)(tseg * 127.0f) - 2; if (ri < 0) ri = 0;
      while (ri < 127 && ((float)ri * (1.0f / 127.0f)) < tseg) ri++;
      int le = ri - 1; if (le < 0) le = 0;
      float tl = (float)le * (1.0f / 127.0f), tr = (float)ri * (1.0f / 127.0f);
      float den = (tr - tl < 1e-8f) ? 1.0f : (tr - tl);
      float wr = (tseg - tl) / den;
      LE[l][m] = le; RI[l][m] = ri; WR[l][m] = wr; WL[l][m] = 1.0f - wr;
    }
  for (int p = 0; p < 2; p++)
    for (int f = 0; f < 4; f++) {
      double fval = (p == 0) ? (double)f
                             : ((f == 0) ? 0.0 : (f == 1) ? 1.0 : (f == 2) ? -2.0 : -1.0);
      double wp = fval * (2.0 * D_PI * 0.125);
      double Wr[8] = {}, Wi[8] = {};
      for (int k = 0; k < 8; k++) {
        double sr = 0.0, si = 0.0;
        for (int m = 0; m < 8; m++) {
          sr += Tch[k][m] * d_cos(node[m] * wp);
          si += Tch[k][m] * (-d_sin(node[m] * wp));
        }
        Wr[k] = sr * 0.125; Wi[k] = si * 0.125;
      }
      for (int l = 0; l < 4; l++) {
        double ph = -2.0 * D_PI * (0.25 * (double)l) * fval;
        double cr = d_cos(ph), ci = d_sin(ph);
        for (int m = 0; m < 8; m++) {
          double coefR = Wr[m] * cr - Wi[m] * ci;
          double coefI = Wr[m] * ci + Wi[m] * cr;
          int le = LE[l][m], ri = RI[l][m];
          if (p == 0) {
            T.ktw[le][32 + f] += (float)(WL[l][m] * coefR);
            T.ktw[le][36 + f] += (float)(WL[l][m] * coefI);
            T.ktw[ri][32 + f] += (float)(WR[l][m] * coefR);
            T.ktw[ri][36 + f] += (float)(WR[l][m] * coefI);
          } else {
            T.cfth[le][f]     += (float)(WL[l][m] * coefR);
            T.cfth[le][4 + f] += (float)(WL[l][m] * coefI);
            T.cfth[ri][f]     += (float)(WR[l][m] * coefR);
            T.cfth[ri][4 + f] += (float)(WR[l][m] * coefI);
          }
        }
      }
    }
  return T;
}

// ---- bf16 split helpers: compile-time (bit-trick RNE) ----
constexpr unsigned short cf2bf(float f) {
  unsigned u = __builtin_bit_cast(unsigned, f);
  u += 0x7FFFu + ((u >> 16) & 1u);
  return (unsigned short)(u >> 16);
}
constexpr float cbf2f(unsigned short h) {
  return __builtin_bit_cast(float, (unsigned)h << 16);
}

// -------- cfth coefficient table (f32) --------
struct CfthT { float v[128][8]; };
constexpr CfthT make_cfth() {
  CfthT C{};
  Tabs T = make_tabs();
  for (int h = 0; h < 128; h++)
    for (int q = 0; q < 8; q++) C.v[h][q] = T.cfth[h][q];
  return C;
}
__constant__ CfthT g_cfth = make_cfth();

// -------- stage A B-table --------
struct alignas(16) BTab {
  unsigned short v[4][2][3][64][8];   // [kstep][hi/lo][jtile][lane][j]
};
constexpr BTab make_btab() {
  BTab B{};
  Tabs T = make_tabs();
  for (int ks = 0; ks < 4; ks++)
    for (int jt = 0; jt < 3; jt++)
      for (int lane = 0; lane < 64; lane++)
        for (int j = 0; j < 8; j++) {
          int col = jt * 16 + (lane & 15);
          int k = ks * 32 + (lane >> 4) * 8 + j;
          float val = (col < 40) ? T.ktw[k][col] : 0.0f;
          unsigned short h = cf2bf(val);
          B.v[ks][0][jt][lane][j] = h;
          B.v[ks][1][jt][lane][j] = cf2bf(val - cbf2f(h));
        }
  return B;
}
__constant__ BTab g_btab = make_btab();

// -------- fwd B-part A-table: TB[64 m=(ri*32+j)][256 k=(2h+u)] --------
struct alignas(16) TBTab {
  unsigned short v[4][8][2][64][8];   // [mtile][kstep][hi/lo][lane][j]
};
constexpr TBTab make_tbtab() {
  TBTab T{};
  double twc[128] = {}, tws[128] = {};
  for (int r = 0; r < 128; r++) {
    double a = 2.0 * D_PI * (double)r / 128.0;
    twc[r] = d_cos(a); tws[r] = d_sin(a);
  }
  for (int mt = 0; mt < 4; mt++)
    for (int ks = 0; ks < 8; ks++)
      for (int lane = 0; lane < 64; lane++)
        for (int js = 0; js < 8; js++) {
          int m = mt * 16 + (lane & 15);
          int j = m & 31, ri = m >> 5;
          int k = ks * 32 + (lane >> 4) * 8 + js;
          int h = k >> 1, u = k & 1;
          int ky = (j < 16) ? j : j + 96;
          int idx = (ky * h) & 127;
          double c = twc[idx], s = tws[idx];
          double val = (ri == 0) ? ((u == 0) ? c : s)
                                 : ((u == 0) ? -s : c);
          float f = (float)val;
          unsigned short hi = cf2bf(f);
          T.v[mt][ks][0][lane][js] = hi;
          T.v[mt][ks][1][lane][js] = cf2bf(f - cbf2f(hi));
        }
  return T;
}
__constant__ TBTab g_tbtab = make_tbtab();

// -------- stage DE GEMM1 A-table --------
struct alignas(16) W1Tab {
  unsigned short v[16][2][2][64][8];  // [mtile][kstep][hi/lo][lane][j]
};
constexpr W1Tab make_w1tab() {
  W1Tab T{};
  double twc[128] = {}, tws[128] = {};
  for (int r = 0; r < 128; r++) {
    double a = 2.0 * D_PI * (double)r / 128.0;
    twc[r] = d_cos(a); tws[r] = d_sin(a);
  }
  for (int mt = 0; mt < 16; mt++)
    for (int ks = 0; ks < 2; ks++)
      for (int lane = 0; lane < 64; lane++)
        for (int j = 0; j < 8; j++) {
          int r = mt * 16 + (lane & 15);
          int k = ks * 32 + (lane >> 4) * 8 + j;
          int jj = k >> 1, u = k & 1;
          int ky = (jj < 16) ? jj : jj + 96;
          int h = r & 127;
          int idx = (ky * h) & 127;
          double c = twc[idx], s = tws[idx];
          double val = (r < 128) ? ((u == 0) ? c : -s)
                                 : ((u == 0) ? s : c);
          float f = (float)(val * (1.0 / 128.0));
          unsigned short hi = cf2bf(f);
          T.v[mt][ks][0][lane][j] = hi;
          T.v[mt][ks][1][lane][j] = cf2bf(f - cbf2f(hi));
        }
  return T;
}
__constant__ W1Tab g_w1tab = make_w1tab();

// -------- stage DE GEMM2 B-table --------
struct alignas(16) W2Tab {
  unsigned short v[8][2][64][8];      // [ntile][hi/lo][lane][j]
};
constexpr W2Tab make_w2tab() {
  W2Tab T{};
  double twc[128] = {}, tws[128] = {};
  for (int r = 0; r < 128; r++) {
    double a = 2.0 * D_PI * (double)r / 128.0;
    twc[r] = d_cos(a); tws[r] = d_sin(a);
  }
  for (int nt = 0; nt < 8; nt++)
    for (int lane = 0; lane < 64; lane++)
      for (int j = 0; j < 8; j++) {
        int w = nt * 16 + (lane & 15);
        int k = (lane >> 4) * 8 + j;
        int kx = k >> 1, u = k & 1;
        double val;
        if (kx == 0) val = (u == 0) ? 1.0 : 0.0;
        else {
          int idx = (kx * w) & 127;
          val = (u == 0) ? 2.0 * twc[idx] : -2.0 * tws[idx];
        }
        float f = (float)(val * (1.0 / 128.0));
        unsigned short hi = cf2bf(f);
        T.v[nt][0][lane][j] = hi;
        T.v[nt][1][lane][j] = cf2bf(f - cbf2f(hi));
      }
  return T;
}
__constant__ W2Tab g_w2tab = make_w2tab();

typedef __attribute__((ext_vector_type(8))) __bf16 bf16x8;
typedef __attribute__((ext_vector_type(8))) unsigned short ushort8;
typedef __attribute__((ext_vector_type(4))) float f32x4;

// ---- runtime bf16 helpers: native casts (v_cvt RNE) ----
__device__ __forceinline__ unsigned short f2bf(float f) {
  return __builtin_bit_cast(unsigned short, (__bf16)f);
}
__device__ __forceinline__ float bf2f(unsigned short h) {
  return (float)__builtin_bit_cast(__bf16, h);
}

// ---------------- fwd: fused stage A + stage B + CFT H-pass ----------------
// Round-17: __launch_bounds__(256, 8) forces VGPR <= 64 -> 8 waves/SIMD ->
// ~8 resident blocks/CU, overlapping one block's load phase with others'
// compute (TLP instead of ILP; rounds 9-13 showed ILP is not the lever).
// Body identical to round-12 best form; compiler re-serializes loads as needed.
__global__ __launch_bounds__(256, 8) void k_fwd(const float* __restrict__ x,
                                                float* __restrict__ xf,
                                                float* __restrict__ flat) {
  __shared__ unsigned xwlp[128][34];   // [h][j=2kx+u] packed (hi | lo<<16)
  __shared__ float cftl[128][9];
  __shared__ float cpart[8][33];
  int t = threadIdx.x;
  int lane = t & 63, wid = t >> 6;
  int bc = blockIdx.x;
  const float* xb = x + (size_t)bc * 16384;
  int r = lane & 15, kg = lane >> 4;
  const float* a0 = xb + (wid * 32 + r) * 128 + kg * 8;
  const float* a1 = a0 + 16 * 128;

  bf16x8 ahi[2][4], alo[2][4];
  #pragma unroll
  for (int tl = 0; tl < 2; tl++) {
    const float* ab = tl ? a1 : a0;
    #pragma unroll
    for (int ks = 0; ks < 4; ks++) {
      float4 v0 = *reinterpret_cast<const float4*>(ab + ks * 32);
      float4 v1 = *reinterpret_cast<const float4*>(ab + ks * 32 + 4);
      float xv[8] = {v0.x, v0.y, v0.z, v0.w, v1.x, v1.y, v1.z, v1.w};
      ushort8 hu, lu;
      #pragma unroll
      for (int j = 0; j < 8; j++) {
        unsigned short h = f2bf(xv[j]);
        hu[j] = h;
        lu[j] = f2bf(xv[j] - bf2f(h));
      }
      ahi[tl][ks] = __builtin_bit_cast(bf16x8, hu);
      alo[tl][ks] = __builtin_bit_cast(bf16x8, lu);
    }
  }

  f32x4 acc[2][3];
  #pragma unroll
  for (int tl = 0; tl < 2; tl++)
    #pragma unroll
    for (int jt = 0; jt < 3; jt++) acc[tl][jt] = f32x4{0.f, 0.f, 0.f, 0.f};
  #pragma unroll
  for (int jt = 0; jt < 3; jt++) {
    #pragma unroll
    for (int ks = 0; ks < 4; ks++) {
      bf16x8 bhi = __builtin_bit_cast(bf16x8,
          *reinterpret_cast<const ushort8*>(&g_btab.v[ks][0][jt][lane][0]));
      bf16x8 blo = __builtin_bit_cast(bf16x8,
          *reinterpret_cast<const ushort8*>(&g_btab.v[ks][1][jt][lane][0]));
      acc[0][jt] = __builtin_amdgcn_mfma_f32_16x16x32_bf16(ahi[0][ks], bhi, acc[0][jt], 0, 0, 0);
      acc[1][jt] = __builtin_amdgcn_mfma_f32_16x16x32_bf16(ahi[1][ks], bhi, acc[1][jt], 0, 0, 0);
      acc[0][jt] = __builtin_amdgcn_mfma_f32_16x16x32_bf16(alo[0][ks], bhi, acc[0][jt], 0, 0, 0);
      acc[1][jt] = __builtin_amdgcn_mfma_f32_16x16x32_bf16(alo[1][ks], bhi, acc[1][jt], 0, 0, 0);
      acc[0][jt] = __builtin_amdgcn_mfma_f32_16x16x32_bf16(ahi[0][ks], blo, acc[0][jt], 0, 0, 0);
      acc[1][jt] = __builtin_amdgcn_mfma_f32_16x16x32_bf16(ahi[1][ks], blo, acc[1][jt], 0, 0, 0);
    }
  }
  {
    int col = lane & 15, rq = lane >> 4;
    #pragma unroll
    for (int tl = 0; tl < 2; tl++) {
      int rt = wid * 2 + tl;
      #pragma unroll
      for (int jt = 0; jt < 3; jt++) {
        #pragma unroll
        for (int i = 0; i < 4; i++) {
          int rl = rt * 16 + rq * 4 + i;
          float v = acc[tl][jt][i];
          if (jt < 2) {
            unsigned short hi = f2bf(v);
            unsigned short lo = f2bf(v - bf2f(hi));
            xwlp[rl][jt * 16 + col] = ((unsigned)lo << 16) | (unsigned)hi;
          } else if (col < 8) {
            cftl[rl][col] = v;
          }
        }
      }
    }
  }
  __syncthreads();

  {
    int o = t & 31, seg = t >> 5;
    int f1 = o >> 3, f2 = (o >> 1) & 3, ri = o & 1;
    float acc2 = 0.f;
    #pragma unroll
    for (int hh = 0; hh < 16; hh++) {
      int h = seg * 16 + hh;
      float rr = cftl[h][f2], im = cftl[h][4 + f2];
      float kr = g_cfth.v[h][f1], ki = g_cfth.v[h][4 + f1];
      float e0 = ri ? ki : kr;
      float e1 = ri ? kr : -ki;
      acc2 = fmaf(rr, e0, fmaf(im, e1, acc2));
    }
    cpart[seg][o] = acc2;
  }

  {
    int kx = lane & 15, g = lane >> 4;
    f32x4 accA = {0.f, 0.f, 0.f, 0.f};
    f32x4 accB = {0.f, 0.f, 0.f, 0.f};
    #pragma unroll
    for (int ks2 = 0; ks2 < 4; ks2++) {
      #pragma unroll
      for (int half = 0; half < 2; half++) {
        int ks = half * 4 + ks2;
        int h0 = ks * 16 + g * 4;
        ushort8 bhU, blU;
        #pragma unroll
        for (int rr = 0; rr < 4; rr++) {
          uint2 p = *reinterpret_cast<const uint2*>(&xwlp[h0 + rr][2 * kx]);
          bhU[2 * rr]     = (unsigned short)(p.x & 0xFFFFu);
          blU[2 * rr]     = (unsigned short)(p.x >> 16);
          bhU[2 * rr + 1] = (unsigned short)(p.y & 0xFFFFu);
          blU[2 * rr + 1] = (unsigned short)(p.y >> 16);
        }
        bf16x8 bhi = __builtin_bit_cast(bf16x8, bhU);
        bf16x8 blo = __builtin_bit_cast(bf16x8, blU);
        bf16x8 thi = __builtin_bit_cast(bf16x8,
            *reinterpret_cast<const ushort8*>(&g_tbtab.v[wid][ks][0][lane][0]));
        bf16x8 tlo = __builtin_bit_cast(bf16x8,
            *reinterpret_cast<const ushort8*>(&g_tbtab.v[wid][ks][1][lane][0]));
        f32x4& acc3 = half ? accB : accA;
        acc3 = __builtin_amdgcn_mfma_f32_16x16x32_bf16(thi, bhi, acc3, 0, 0, 0);
        acc3 = __builtin_amdgcn_mfma_f32_16x16x32_bf16(tlo, bhi, acc3, 0, 0, 0);
        acc3 = __builtin_amdgcn_mfma_f32_16x16x32_bf16(thi, blo, acc3, 0, 0, 0);
      }
    }
    f32x4 accS = accA + accB;
    #pragma unroll
    for (int i = 0; i < 4; i++) {
      int m = wid * 16 + (lane >> 4) * 4 + i;
      int j = m & 31, ri = m >> 5;
      xf[((size_t)bc * 32 + j) * 32 + kx * 2 + ri] = accS[i];
    }
  }
  __syncthreads();

  if (t < 32) {
    float sum = 0.f;
    #pragma unroll
    for (int seg = 0; seg < 8; seg++) sum += cpart[seg][t];
    int b = bc >> 6, c = bc & 63;
    int f1 = t >> 3, f2 = (t >> 1) & 3, ri = t & 1;
    flat[(size_t)b * 2048 + ((c * 4 + f1) * 4 + f2) * 2 + ri] = sum;
  }
}

// ---------------- MLP stage 1: flat -> hs ----------------
__global__ __launch_bounds__(256) void k_mlp1(const float* __restrict__ flat,
                                              const float* __restrict__ w1,
                                              const float* __restrict__ b1,
                                              float* __restrict__ hs) {
  __shared__ float part[4][64];
  int bid = blockIdx.x;
  int b = bid >> 2, oc = bid & 3;
  int t = threadIdx.x;
  int ol = t & 63, kc = t >> 6;
  int o = oc * 64 + ol;
  const float* fb = flat + (size_t)b * 2048 + kc * 512;
  const float* wb = w1 + (size_t)(kc * 512) * 256 + o;
  float acc = 0.f;
  for (int k = 0; k < 512; k++) acc = fmaf(fb[k], wb[(size_t)k * 256], acc);
  part[kc][ol] = acc;
  __syncthreads();
  if (t < 64) {
    float a = part[0][t] + part[1][t] + part[2][t] + part[3][t] + b1[oc * 64 + t];
    hs[(size_t)b * 256 + oc * 64 + t] = 0.5f * a * (1.0f + erff(a * 0.70710678118654752f));
  }
}

// ---------------- MLP stage 2: hs -> corr ----------------
__global__ void k_mlp2(const float* __restrict__ hs,
                       const float* __restrict__ w2,
                       const float* __restrict__ b2,
                       float* __restrict__ corr) {
  int b = blockIdx.x, t = threadIdx.x;   // 64 threads
  const float* hb = hs + (size_t)b * 256;
  float acc = b2[t];
  for (int k = 0; k < 256; k++) acc = fmaf(hb[k], w2[(size_t)k * 64 + t], acc);
  corr[(size_t)b * 64 + t] = acc;
}

// ---------------- stage C: mode-mixing einsum over C, 4 b's per block ----------------
__global__ __launch_bounds__(256) void k_stageC(const float* __restrict__ xf,
                                                const float* __restrict__ w1,
                                                const float* __restrict__ w2,
                                                float* __restrict__ outft) {
  __shared__ float xfs[4][2048];       // [bb][c*32 + kx*2+u]
  int bid = blockIdx.x;
  int xcd = bid & 7, kk = bid >> 3;    // kk 0..31
  int j = xcd * 4 + (kk & 3);
  int bq = kk >> 2;                    // 0..7
  int b0 = bq * 4;
  int t = threadIdx.x;

  #pragma unroll
  for (int bb = 0; bb < 4; bb++) {
    int b = b0 + bb;
    #pragma unroll
    for (int k2 = 0; k2 < 4; k2++) {
      int id = t + k2 * 256;           // 1024 float2 per b
      int c = id >> 4, kxi = id & 15;
      const float2 v = *reinterpret_cast<const float2*>(
          xf + (((size_t)b * 64 + c) * 32 + j) * 32 + kxi * 2);
      reinterpret_cast<float2*>(&xfs[bb][0])[id] = v;
    }
  }
  __syncthreads();

  int kx = t & 15, og = t >> 4;
  const float* wsel = (j < 16) ? w1 : w2;
  int jr = (j < 16) ? j : j - 16;
  float aR[4][4], aI[4][4];            // [bb][i]
  #pragma unroll
  for (int bb = 0; bb < 4; bb++)
    #pragma unroll
    for (int i = 0; i < 4; i++) { aR[bb][i] = 0.f; aI[bb][i] = 0.f; }

  for (int c = 0; c < 64; c++) {
    float2 wv[4];
    #pragma unroll
    for (int i = 0; i < 4; i++) {
      int o = og * 4 + i;
      wv[i] = *reinterpret_cast<const float2*>(
          wsel + ((((size_t)c * 64 + o) * 16 + jr) * 16 + kx) * 2);
    }
    #pragma unroll
    for (int bb = 0; bb < 4; bb++) {
      float xr = xfs[bb][c * 32 + kx * 2], xi = xfs[bb][c * 32 + kx * 2 + 1];
      #pragma unroll
      for (int i = 0; i < 4; i++) {
        aR[bb][i] = fmaf(xr, wv[i].x, fmaf(-xi, wv[i].y, aR[bb][i]));
        aI[bb][i] = fmaf(xr, wv[i].y, fmaf(xi, wv[i].x, aI[bb][i]));
      }
    }
  }

  int boff = (j >> 4) * 512 + ((((j >> 2) & 3) << 4) | kx) * 8 + (j & 3) * 2;
  #pragma unroll
  for (int bb = 0; bb < 4; bb++) {
    int b = b0 + bb;
    #pragma unroll
    for (int i = 0; i < 4; i++) {
      int o = og * 4 + i;
      float2* dst = reinterpret_cast<float2*>(outft + (size_t)(b * 64 + o) * 1024 + boff);
      *dst = make_float2(aR[bb][i], aI[bb][i]);
    }
  }
}

// ---------------- stage DE: two chained split-bf16 MFMA GEMMs per (b,o) ----------------
__global__ __launch_bounds__(256) void k_stageDE(const float* __restrict__ outft,
                                                 const float* __restrict__ corr,
                                                 float* __restrict__ out) {
  __shared__ float Yl[256 * 17];
  int t = threadIdx.x;
  int lane = t & 63, wid = t >> 6;
  int bo = blockIdx.x;
  const float* src = outft + (size_t)bo * 1024;

  bf16x8 shi[2], slo[2];
  #pragma unroll
  for (int ks = 0; ks < 2; ks++) {
    float4 v0 = *reinterpret_cast<const float4*>(src + ks * 512 + lane * 8);
    float4 v1 = *reinterpret_cast<const float4*>(src + ks * 512 + lane * 8 + 4);
    float xv[8] = {v0.x, v0.y, v0.z, v0.w, v1.x, v1.y, v1.z, v1.w};
    ushort8 hu, lu;
    #pragma unroll
    for (int j = 0; j < 8; j++) {
      unsigned short h = f2bf(xv[j]);
      hu[j] = h;
      lu[j] = f2bf(xv[j] - bf2f(h));
    }
    shi[ks] = __builtin_bit_cast(bf16x8, hu);
    slo[ks] = __builtin_bit_cast(bf16x8, lu);
  }

  #pragma unroll
  for (int mtl = 0; mtl < 4; mtl++) {
    int mt = wid * 4 + mtl;
    f32x4 acc = {0.f, 0.f, 0.f, 0.f};
    #pragma unroll
    for (int ks = 0; ks < 2; ks++) {
      bf16x8 whi = __builtin_bit_cast(bf16x8,
          *reinterpret_cast<const ushort8*>(&g_w1tab.v[mt][ks][0][lane][0]));
      bf16x8 wlo = __builtin_bit_cast(bf16x8,
          *reinterpret_cast<const ushort8*>(&g_w1tab.v[mt][ks][1][lane][0]));
      acc = __builtin_amdgcn_mfma_f32_16x16x32_bf16(whi, shi[ks], acc, 0, 0, 0);
      acc = __builtin_amdgcn_mfma_f32_16x16x32_bf16(wlo, shi[ks], acc, 0, 0, 0);
      acc = __builtin_amdgcn_mfma_f32_16x16x32_bf16(whi, slo[ks], acc, 0, 0, 0);
    }
    #pragma unroll
    for (int i = 0; i < 4; i++)
      Yl[(mt * 16 + (lane >> 4) * 4 + i) * 17 + (lane & 15)] = acc[i];
  }
  __syncthreads();

  float corrv = corr[bo];
  float* obase = out + (size_t)bo * 16384;

  #pragma unroll
  for (int mtl = 0; mtl < 2; mtl++) {
    int mt2 = wid * 2 + mtl;
    int h = mt2 * 16 + (lane & 15);
    ushort8 ahiU, aloU;
    #pragma unroll
    for (int j = 0; j < 8; j++) {
      int k = (lane >> 4) * 8 + j;
      float v = Yl[((k & 1) * 128 + h) * 17 + (k >> 1)];
      unsigned short hi = f2bf(v);
      ahiU[j] = hi;
      aloU[j] = f2bf(v - bf2f(hi));
    }
    bf16x8 ahi = __builtin_bit_cast(bf16x8, ahiU);
    bf16x8 alo = __builtin_bit_cast(bf16x8, aloU);
    #pragma unroll
    for (int nt = 0; nt < 8; nt++) {
      bf16x8 bhi = __builtin_bit_cast(bf16x8,
          *reinterpret_cast<const ushort8*>(&g_w2tab.v[nt][0][lane][0]));
      bf16x8 blo = __builtin_bit_cast(bf16x8,
          *reinterpret_cast<const ushort8*>(&g_w2tab.v[nt][1][lane][0]));
      f32x4 acc = {corrv, corrv, corrv, corrv};
      acc = __builtin_amdgcn_mfma_f32_16x16x32_bf16(ahi, bhi, acc, 0, 0, 0);
      acc = __builtin_amdgcn_mfma_f32_16x16x32_bf16(alo, bhi, acc, 0, 0, 0);
      acc = __builtin_amdgcn_mfma_f32_16x16x32_bf16(ahi, blo, acc, 0, 0, 0);
      #pragma unroll
      for (int i = 0; i < 4; i++)
        __builtin_nontemporal_store(acc[i],
            &obase[(mt2 * 16 + (lane >> 4) * 4 + i) * 128 + nt * 16 + (lane & 15)]);
    }
  }
}

extern "C" void kernel_launch(void* const* d_in, const int* in_sizes, int n_in,
                              void* d_out, int out_size, void* d_ws, size_t ws_size,
                              hipStream_t stream) {
  const float* x   = (const float*)d_in[0];
  const float* w1  = (const float*)d_in[1];
  const float* w2  = (const float*)d_in[2];
  const float* l1w = (const float*)d_in[3];
  const float* l1b = (const float*)d_in[4];
  const float* l2w = (const float*)d_in[5];
  const float* l2b = (const float*)d_in[6];
  float* out = (float*)d_out;
  float* ws  = (float*)d_ws;

  float* flat  = ws + WSO_FLAT;
  float* corr  = ws + WSO_CORR;
  float* hs    = ws + WSO_HS;
  float* xf    = ws + WSO_XF;
  float* outft = ws + WSO_OUTFT;

  k_fwd<<<dim3(2048), dim3(256), 0, stream>>>(x, xf, flat);
  k_mlp1<<<dim3(128), dim3(256), 0, stream>>>(flat, l1w, l1b, hs);
  k_mlp2<<<dim3(32), dim3(64), 0, stream>>>(hs, l2w, l2b, corr);
  k_stageC<<<dim3(256), dim3(256), 0, stream>>>(xf, w1, w2, outft);
  k_stageDE<<<dim3(2048), dim3(256), 0, stream>>>(outft, corr, out);
}